// Round 5
// baseline (211.434 us; speedup 1.0000x reference)
//
#include <hip/hip_runtime.h>
#include <cmath>

typedef _Float16 f16x8 __attribute__((ext_vector_type(8)));
typedef _Float16 f16x4 __attribute__((ext_vector_type(4)));
typedef float    f32x16 __attribute__((ext_vector_type(16)));

constexpr int NBATCH = 32;
constexpr int NSEQ   = 4096;
constexpr int NCH    = 128;
constexpr int NEXP   = 64;
constexpr int NE2    = 128;
constexpr int DIN    = 2 * NSEQ;       // 8192
constexpr int ROWS   = NBATCH * NCH;   // 4096
constexpr int KCH    = 16;             // split-K chunks (512 features each)
constexpr int KT     = 16;             // K-tiles per chunk (32 features each)
constexpr float LOSC = 2048.0f;
constexpr float INV_LOSC = 1.0f / 2048.0f;

// ws layout: partials 32 MiB @0 ; Whi 2 MiB @32Mi ; Wlo 2 MiB @34Mi
constexpr size_t WS_WHI = 32ull << 20;
constexpr size_t WS_WLO = 34ull << 20;

// [128][32] f16 tile, rows 64B: XOR 16B-granule with (row>>1)&3 (G4).
__device__ __forceinline__ int swz_f16(int row, int g) {
    return row * 32 + ((g ^ ((row >> 1) & 3)) << 3);
}

__device__ __forceinline__ void gload_lds16(const void* g, void* l) {
    __builtin_amdgcn_global_load_lds(
        (const __attribute__((address_space(1))) unsigned int*)g,
        (__attribute__((address_space(3))) unsigned int*)l, 16, 0, 0);
}

// ---------------------------------------------------------------------------
// Prep: split W into f16 hi/lo with the granule swizzle pre-baked (rule #21:
// linear LDS dest + pre-permuted global source + swizzled ds_read).
// ---------------------------------------------------------------------------
__global__ __launch_bounds__(256)
void wprep_kernel(const float* __restrict__ Wm, const float* __restrict__ Wn,
                  _Float16* __restrict__ Whi, _Float16* __restrict__ Wlo)
{
    const int idx = (blockIdx.x * 256 + threadIdx.x) * 4;  // f32 index, 1M total
    const int row = idx >> 13;
    const int f   = idx & 8191;
    const float* src = (row < NEXP) ? (Wm + (size_t)row * DIN + f)
                                    : (Wn + (size_t)(row - NEXP) * DIN + f);
    const float4 v = *(const float4*)src;
    const int g  = (f >> 3) & 3;
    const int fs = (f & ~0x18) | ((g ^ ((row >> 1) & 3)) << 3);
    float vv[4] = { v.x, v.y, v.z, v.w };
    f16x4 h, l;
#pragma unroll
    for (int j = 0; j < 4; ++j) {
        _Float16 hj = (_Float16)vv[j];
        h[j] = hj;
        l[j] = (_Float16)((vv[j] - (float)hj) * LOSC);
    }
    *(f16x4*)&Whi[(size_t)row * 8192 + fs] = h;
    *(f16x4*)&Wlo[(size_t)row * 8192 + fs] = l;
}

// ---------------------------------------------------------------------------
// GEMM: split-f16 MFMA, counted-vmcnt pipeline (T4) + depth-2 x prefetch (T14).
// Grid 512 (XCD swizzle); block 256 = 4 waves 2x2; tile 128(c) x 128(e) x 512.
// Steady-state outstanding vmem/wave: {x(t+1):8, W(t+1):4, x(t+2):8} — the
// barrier never drains vmcnt to 0 mid-loop.
// ---------------------------------------------------------------------------
__global__ __launch_bounds__(256, 2)
void gemm_kernel(const float* __restrict__ x,
                 const _Float16* __restrict__ Whi,
                 const _Float16* __restrict__ Wlo,
                 float* __restrict__ partials)
{
    // XCD swizzle: each XCD gets kc in {x, x+8} for all 32 b -> W L2-resident
    const int l    = blockIdx.x;
    const int slot = l >> 3;
    const int kc   = (l & 7) + 8 * (slot & 1);
    const int b    = slot >> 1;

    const int tid  = threadIdx.x;
    const int lane = tid & 63;
    const int wave = tid >> 6;
    const int wm   = wave >> 1;
    const int wn   = wave & 1;

    __shared__ _Float16 lds[2 * 16384];   // 2 bufs x {Ah,Al,Bh,Bl}[128][32]

    f32x16 acc1[2][2], acc2[2][2];
#pragma unroll
    for (int mi = 0; mi < 2; ++mi)
#pragma unroll
        for (int ni = 0; ni < 2; ++ni)
#pragma unroll
            for (int r = 0; r < 16; ++r) { acc1[mi][ni][r] = 0.f; acc2[mi][ni][r] = 0.f; }

    const float* xchunk = x + (size_t)b * (NSEQ * 256) + (size_t)kc * (256 * 256);
    const int c    = tid & 127;
    const int gsel = tid >> 7;
    const int fb0  = kc * 512;
    const int e_ld = lane >> 2;
    const int goff = (lane & 3) * 8;

    float2 xr[2][8];   // depth-2 x prefetch reg sets (statically indexed via full unroll)

    auto load_x = [&](int t, float2 (&dst)[8]) {
#pragma unroll
        for (int u = 0; u < 2; ++u) {
            const int g = u * 2 + gsel;
#pragma unroll
            for (int i = 0; i < 4; ++i)
                dst[u * 4 + i] = *(const float2*)(xchunk + (size_t)(t * 16 + g * 4 + i) * 256 + c * 2);
        }
    };
    auto write_x = [&](int buf, float2 (&src)[8]) {
        _Float16* Ah = lds + buf * 16384;
        _Float16* Al = Ah + 4096;
#pragma unroll
        for (int u = 0; u < 2; ++u) {
            const int g = u * 2 + gsel;
            f16x8 h, lo;
#pragma unroll
            for (int i = 0; i < 4; ++i) {
                float a0 = src[u * 4 + i].x, a1 = src[u * 4 + i].y;
                _Float16 h0 = (_Float16)a0, h1 = (_Float16)a1;
                h[2 * i] = h0; h[2 * i + 1] = h1;
                lo[2 * i]     = (_Float16)((a0 - (float)h0) * LOSC);
                lo[2 * i + 1] = (_Float16)((a1 - (float)h1) * LOSC);
            }
            const int off = swz_f16(c, g);
            *(f16x8*)&Ah[off] = h;
            *(f16x8*)&Al[off] = lo;
        }
    };
    auto issue_W = [&](int t, int buf) {
        const int fb = fb0 + t * 32;
        _Float16* Bh = lds + buf * 16384 + 8192;
        _Float16* Bl = Bh + 4096;
#pragma unroll
        for (int q = 0; q < 2; ++q) {
            const int e0 = wave * 32 + q * 16;
            gload_lds16(Whi + (size_t)(e0 + e_ld) * 8192 + fb + goff, Bh + e0 * 32);
            gload_lds16(Wlo + (size_t)(e0 + e_ld) * 8192 + fb + goff, Bl + e0 * 32);
        }
    };

    // ---- prologue: establish invariant {outstanding = x(1):8} ----
    issue_W(0, 0);
    load_x(0, xr[0]);
    load_x(1, xr[1]);
    write_x(0, xr[0]);   // compiler auto-waits x(0) regs; FIFO retire covers W(0) too
    asm volatile("s_waitcnt lgkmcnt(0)" ::: "memory");
    __builtin_amdgcn_s_barrier();
    __builtin_amdgcn_sched_barrier(0);

#pragma unroll
    for (int t = 0; t < KT; ++t) {
        const int buf = t & 1;

        // issue-early: next W tile (DMA into buf^1.B) + x(t+2) reg loads
        if (t + 1 < KT) issue_W(t + 1, buf ^ 1);
        if (t + 2 < KT) load_x(t + 2, xr[buf]);       // xr[t&1] freed last iter
        __builtin_amdgcn_sched_barrier(0);            // pin issues above MFMA phase

        const _Float16* Ah = lds + buf * 16384;
        const _Float16* Al = Ah + 4096;
        const _Float16* Bh = Ah + 8192;
        const _Float16* Bl = Ah + 12288;
#pragma unroll
        for (int kk = 0; kk < 2; ++kk) {
            const int gk = kk * 2 + (lane >> 5);
            f16x8 ah[2], al[2], bh[2], bl[2];
#pragma unroll
            for (int i = 0; i < 2; ++i) {
                const int oa = swz_f16(wm * 64 + i * 32 + (lane & 31), gk);
                const int ob = swz_f16(wn * 64 + i * 32 + (lane & 31), gk);
                ah[i] = *(const f16x8*)&Ah[oa];
                al[i] = *(const f16x8*)&Al[oa];
                bh[i] = *(const f16x8*)&Bh[ob];
                bl[i] = *(const f16x8*)&Bl[ob];
            }
#pragma unroll
            for (int mi = 0; mi < 2; ++mi)
#pragma unroll
                for (int ni = 0; ni < 2; ++ni) {
                    acc1[mi][ni] = __builtin_amdgcn_mfma_f32_32x32x16_f16(ah[mi], bh[ni], acc1[mi][ni], 0, 0, 0);
                    acc2[mi][ni] = __builtin_amdgcn_mfma_f32_32x32x16_f16(ah[mi], bl[ni], acc2[mi][ni], 0, 0, 0);
                    acc2[mi][ni] = __builtin_amdgcn_mfma_f32_32x32x16_f16(al[mi], bh[ni], acc2[mi][ni], 0, 0, 0);
                }
        }

        if (t + 1 < KT) {
            write_x(buf ^ 1, xr[buf ^ 1]);            // auto-wait retires thru x(t+1)
            if (t + 2 < KT) asm volatile("s_waitcnt vmcnt(8) lgkmcnt(0)" ::: "memory");
            else            asm volatile("s_waitcnt vmcnt(0) lgkmcnt(0)" ::: "memory");
            __builtin_amdgcn_s_barrier();             // W(t+1) landed, x(t+1) published
            __builtin_amdgcn_sched_barrier(0);        // no reads hoist above barrier
        }
    }

    // epilogue: C/D layout (m74/m101): col=lane&31, row=(r&3)+8*(r>>2)+4*(lane>>5)
    float* outp = partials + ((size_t)kc * ROWS + (size_t)b * NCH) * NE2;
#pragma unroll
    for (int mi = 0; mi < 2; ++mi)
#pragma unroll
        for (int ni = 0; ni < 2; ++ni)
#pragma unroll
            for (int r = 0; r < 16; ++r) {
                const int rloc = (r & 3) + 8 * (r >> 2) + 4 * (lane >> 5);
                const int crow = wm * 64 + mi * 32 + rloc;
                const int e    = wn * 64 + ni * 32 + (lane & 31);
                outp[(size_t)crow * NE2 + e] = acc1[mi][ni][r] + acc2[mi][ni][r] * INV_LOSC;
            }
}

// ---------------------------------------------------------------------------
// Gate: reduce split-K partials, bias, softplus, exact kthvalue top-2 keep,
// masked softmax. Block = 2 rows x 128 experts.
// ---------------------------------------------------------------------------
__global__ __launch_bounds__(256)
void gate_kernel(const float* __restrict__ partials,
                 const float* __restrict__ bm,
                 const float* __restrict__ bn,
                 float* __restrict__ out)
{
    const int tid  = threadIdx.x;
    const int rl   = tid >> 7;
    const int e    = tid & 127;
    const int lane = tid & 63;
    const int row  = blockIdx.x * 2 + rl;

    const float* p = partials + (size_t)row * NE2 + e;
    float s = 0.f;
#pragma unroll
    for (int kc = 0; kc < KCH; ++kc)
        s += p[(size_t)kc * ROWS * NE2];

    __shared__ float spl[2][64];
    if (e >= NEXP) {
        float nz = s + bn[lane];
        spl[rl][lane] = fmaxf(nz, 0.f) + log1pf(expf(-fabsf(nz)));
    }
    __syncthreads();
    if (e < NEXP) {
        float g = s + bm[lane] + spl[rl][lane];

        float v  = g;
        float m1 = v;
#pragma unroll
        for (int o = 32; o > 0; o >>= 1) m1 = fmaxf(m1, __shfl_xor(m1, o));
        unsigned long long b1 = __ballot(v == m1);
        int l1 = __ffsll(b1) - 1;
        if (lane == l1) v = -INFINITY;
        float m2 = v;
#pragma unroll
        for (int o = 32; o > 0; o >>= 1) m2 = fmaxf(m2, __shfl_xor(m2, o));
        unsigned long long b2 = __ballot(v == m2);
        int l2 = __ffsll(b2) - 1;
        if (lane == l2) v = -INFINITY;
        float kth = v;
#pragma unroll
        for (int o = 32; o > 0; o >>= 1) kth = fmaxf(kth, __shfl_xor(kth, o));

        float ev  = (g > kth) ? expf(g - m1) : 0.f;
        float den = ev;
#pragma unroll
        for (int o = 32; o > 0; o >>= 1) den += __shfl_xor(den, o);
        out[(size_t)row * NEXP + lane] = ev / den;
    }
}

extern "C" void kernel_launch(void* const* d_in, const int* in_sizes, int n_in,
                              void* d_out, int out_size, void* d_ws, size_t ws_size,
                              hipStream_t stream)
{
    const float* x  = (const float*)d_in[0];
    const float* Wm = (const float*)d_in[1];
    const float* bm = (const float*)d_in[2];
    const float* Wn = (const float*)d_in[3];
    const float* bn = (const float*)d_in[4];
    float* out      = (float*)d_out;

    float*     partials = (float*)d_ws;                       // 32 MiB
    _Float16*  Whi      = (_Float16*)((char*)d_ws + WS_WHI);  // 2 MiB
    _Float16*  Wlo      = (_Float16*)((char*)d_ws + WS_WLO);  // 2 MiB

    wprep_kernel<<<1024, 256, 0, stream>>>(Wm, Wn, Whi, Wlo);
    gemm_kernel<<<512, 256, 0, stream>>>(x, Whi, Wlo, partials);
    gate_kernel<<<ROWS / 2, 256, 0, stream>>>(partials, bm, bn, out);
}